// Round 5
// baseline (138.992 us; speedup 1.0000x reference)
//
#include <hip/hip_runtime.h>
#include <math.h>

// MarketRegimeHMM forward via chunked associative scan — linear-domain semiring,
// base-2 scales, REGISTER-ONLY pipeline:
//   k_prep  : 1 block; preprocess ~713 params into ws (scaled for exp2 forms).
//   k_build : one LANE per chunk (C=4): build 4 E matrices sequentially in
//             registers (params via uniform s_load -> SGPR operands), fold in
//             place (125 FMA/matmat), rescale-by-max, write R[b][c] (+log2
//             scale) and bf16 E records.  NO LDS, NO barriers.
//   k_scan  : one block per b: 3-level scan over 1024 records
//             (fold4 -> fold8 -> serial 32, then prefixes back down) ->
//             start[b][c] (linear alpha + log2 scale) and LL[b].
//   k_alpha : one lane per chunk: stream bf16 E from ws, 25 FMA + 5 log2 per t.
//             (fallback variant rebuilds E when ws is too small.)

namespace {

constexpr int kS = 5, kD = 16, kB = 256, kT = 4096;
constexpr int kC = 4, kNC = 1024;  // chunks per batch element

constexpr float kL2E = 1.4426950408889634f;  // 1/ln2
constexpr float kLn2 = 0.6931471805599453f;

// prep region offsets (floats)
constexpr int P_EA = 0;    // 80  -0.5*inv_v/ln2            [s*16+d]
constexpr int P_MU = 80;   // 80  means (raw)               [s*16+d]
constexpr int P_EC = 160;  // 5   -0.5*(16ln2pi + sum lv)/ln2
constexpr int P_LN = 168;  // 5   log2_softmax(log_initial)
constexpr int P_W1 = 176;  // 200 (2/ln2)*W1                [(i*10+h)*4+f]
constexpr int P_B1 = 376;  // 50  (2/ln2)*b1                [i*10+h]
constexpr int P_W2 = 432;  // 250 W2/ln2                    [(i*5+j)*10+h]
constexpr int P_B2 = 688;  // 25  (b2+tbias)/ln2            [i*5+j]
constexpr int P_TOT = 1024;  // reserved floats (4KB)

__device__ __forceinline__ float max5(float a0, float a1, float a2, float a3, float a4) {
  return fmaxf(fmaxf(fmaxf(a0, a1), fmaxf(a2, a3)), a4);
}

__device__ __forceinline__ void loadObs(const float* __restrict__ obs_bt, float o[kD]) {
  const float4* o4 = reinterpret_cast<const float4*>(obs_bt);
  float4 v0 = o4[0], v1 = o4[1], v2 = o4[2], v3 = o4[3];
  o[0] = v0.x; o[1] = v0.y; o[2] = v0.z; o[3] = v0.w;
  o[4] = v1.x; o[5] = v1.y; o[6] = v1.z; o[7] = v1.w;
  o[8] = v2.x; o[9] = v2.y; o[10] = v2.z; o[11] = v2.w;
  o[12] = v3.x; o[13] = v3.y; o[14] = v3.z; o[15] = v3.w;
}

__device__ __forceinline__ unsigned bf16bits(float x) {
  unsigned u = __float_as_uint(x);
  return (u + 0x7fffu + ((u >> 16) & 1u)) >> 16;  // RTNE
}

__global__ void k_prep(const float* __restrict__ means, const float* __restrict__ lv,
                       const float* __restrict__ linit, const float* __restrict__ tbias,
                       const float* __restrict__ W1g, const float* __restrict__ b1g,
                       const float* __restrict__ W2g, const float* __restrict__ b2g,
                       float* __restrict__ P) {
  const int tid = threadIdx.x;  // 256
  if (tid < 80) {
    float iv = __expf(-lv[tid]);
    P[P_EA + tid] = -0.5f * kL2E * iv;
    P[P_MU + tid] = means[tid];
  }
  if (tid >= 80 && tid < 85) {
    const int s = tid - 80;
    float acc = 0.f;
#pragma unroll
    for (int d = 0; d < 16; ++d) acc += lv[s * 16 + d];
    P[P_EC + s] = -0.5f * kL2E * (29.406033062549525f + acc);  // 16*ln(2pi)+sum
    float l0 = linit[0], l1 = linit[1], l2 = linit[2], l3 = linit[3], l4 = linit[4];
    float m = max5(l0, l1, l2, l3, l4);
    float se = __expf(l0 - m) + __expf(l1 - m) + __expf(l2 - m) +
               __expf(l3 - m) + __expf(l4 - m);
    P[P_LN + s] = kL2E * (linit[s] - (m + __logf(se)));
  }
  if (tid < 200) P[P_W1 + tid] = (2.0f * kL2E) * W1g[tid];
  if (tid < 50)  P[P_B1 + tid] = (2.0f * kL2E) * b1g[tid];
  if (tid < 250) P[P_W2 + tid] = kL2E * W2g[tid];
  if (tid < 25)  P[P_B2 + tid] = kL2E * (b2g[tid] + tbias[tid]);
}

// E_t = softmax(logits) * diag(exp2(le2 - c)), c = max_j le2[j]
// All pp[] reads are wave-uniform with literal offsets -> s_load -> SGPR operand.
__device__ __forceinline__ void buildE(const float* __restrict__ obs,
                                       const float* __restrict__ feat,
                                       const float* __restrict__ pp,
                                       size_t bt, float E[25], float& c) {
  float o[16];
  loadObs(obs + bt * kD, o);
  float le[5];
#pragma unroll
  for (int s = 0; s < 5; ++s) {
    float acc = pp[P_EC + s];
#pragma unroll
    for (int d = 0; d < 16; ++d) {
      float dd = o[d] - pp[P_MU + s * 16 + d];
      acc = fmaf(dd, dd * pp[P_EA + s * 16 + d], acc);
    }
    le[s] = acc;
  }
  c = max5(le[0], le[1], le[2], le[3], le[4]);
  float eml[5];
#pragma unroll
  for (int j = 0; j < 5; ++j) eml[j] = exp2f(le[j] - c);
  const float4 f = *reinterpret_cast<const float4*>(feat + bt * 4);
#pragma unroll
  for (int i = 0; i < 5; ++i) {
    float hv[10];
#pragma unroll
    for (int h = 0; h < 10; ++h) {
      float acc = f.x * pp[P_W1 + (i * 10 + h) * 4 + 0];
      acc = fmaf(f.y, pp[P_W1 + (i * 10 + h) * 4 + 1], acc);
      acc = fmaf(f.z, pp[P_W1 + (i * 10 + h) * 4 + 2], acc);
      acc = fmaf(f.w, pp[P_W1 + (i * 10 + h) * 4 + 3], acc);
      acc = acc + pp[P_B1 + i * 10 + h];
      float e = exp2f(acc);                                  // = exp(2x)
      hv[h] = 1.f - 2.f * __builtin_amdgcn_rcpf(e + 1.f);    // tanh
    }
    float eg[5], se = 0.f;
#pragma unroll
    for (int j = 0; j < 5; ++j) {
      float acc = hv[0] * pp[P_W2 + (i * 5 + j) * 10 + 0];
#pragma unroll
      for (int h = 1; h < 10; ++h)
        acc = fmaf(hv[h], pp[P_W2 + (i * 5 + j) * 10 + h], acc);
      acc = acc + pp[P_B2 + i * 5 + j];
      eg[j] = exp2f(acc);  // logits bounded (~+-21 in log2) -> no max-sub
      se += eg[j];
    }
    const float rs = __builtin_amdgcn_rcpf(se);
#pragma unroll
    for (int j = 0; j < 5; ++j) E[i * 5 + j] = eg[j] * rs * eml[j];
  }
}

// pseudo-record for t=0: ones (x) E0 = linear alpha_0 (log2-scaled by c)
__device__ __forceinline__ void buildE0(const float* __restrict__ obs,
                                        const float* __restrict__ pp, int b,
                                        float E[25], float& c) {
  float o[16];
  loadObs(obs + (size_t)b * kT * kD, o);
  float v[5];
#pragma unroll
  for (int s = 0; s < 5; ++s) {
    float acc = pp[P_EC + s];
#pragma unroll
    for (int d = 0; d < 16; ++d) {
      float dd = o[d] - pp[P_MU + s * 16 + d];
      acc = fmaf(dd, dd * pp[P_EA + s * 16 + d], acc);
    }
    v[s] = acc + pp[P_LN + s];
  }
  c = max5(v[0], v[1], v[2], v[3], v[4]);
  float e[5];
#pragma unroll
  for (int j = 0; j < 5; ++j) e[j] = 0.2f * exp2f(v[j] - c);
#pragma unroll
  for (int i = 0; i < 5; ++i)
#pragma unroll
    for (int j = 0; j < 5; ++j) E[i * 5 + j] = e[j];
}

__device__ __forceinline__ void matmat5(float R[25], const float E[25]) {
#pragma unroll
  for (int i = 0; i < 5; ++i) {
    const float r0 = R[i * 5 + 0], r1 = R[i * 5 + 1], r2 = R[i * 5 + 2];
    const float r3 = R[i * 5 + 3], r4 = R[i * 5 + 4];
#pragma unroll
    for (int j = 0; j < 5; ++j) {
      float acc = r0 * E[j];
      acc = fmaf(r1, E[5 + j], acc);
      acc = fmaf(r2, E[10 + j], acc);
      acc = fmaf(r3, E[15 + j], acc);
      acc = fmaf(r4, E[20 + j], acc);
      R[i * 5 + j] = acc;
    }
  }
}

__device__ __forceinline__ void rescale25(float R[25], float& sc) {
  float m = R[0];
#pragma unroll
  for (int e = 1; e < 25; ++e) m = fmaxf(m, R[e]);
  m = fmaxf(m, 1e-30f);
  const float r = __builtin_amdgcn_rcpf(m);
#pragma unroll
  for (int e = 0; e < 25; ++e) R[e] *= r;
  sc += __log2f(m);
}

__device__ __forceinline__ void vecmat5(float a[5], const float M[25]) {
  float o[5];
#pragma unroll
  for (int j = 0; j < 5; ++j) {
    float acc = a[0] * M[j];
    acc = fmaf(a[1], M[5 + j], acc);
    acc = fmaf(a[2], M[10 + j], acc);
    acc = fmaf(a[3], M[15 + j], acc);
    acc = fmaf(a[4], M[20 + j], acc);
    o[j] = acc;
  }
#pragma unroll
  for (int j = 0; j < 5; ++j) a[j] = o[j];
}

__device__ __forceinline__ void rescale5(float a[5], float& ls) {
  const float m = fmaxf(max5(a[0], a[1], a[2], a[3], a[4]), 1e-30f);
  const float r = __builtin_amdgcn_rcpf(m);
#pragma unroll
  for (int j = 0; j < 5; ++j) a[j] *= r;
  ls += __log2f(m);
}

__device__ __forceinline__ void packE(uint4* __restrict__ wsE, size_t t,
                                      const float E[25], float c) {
  unsigned d[14];
#pragma unroll
  for (int q = 0; q < 12; ++q)
    d[q] = bf16bits(E[2 * q]) | (bf16bits(E[2 * q + 1]) << 16);
  const unsigned cb = __float_as_uint(c);
  d[12] = bf16bits(E[24]) | (cb << 16);
  d[13] = cb >> 16;
  uint4* wp = wsE + t * 4;
  wp[0] = make_uint4(d[0], d[1], d[2], d[3]);
  wp[1] = make_uint4(d[4], d[5], d[6], d[7]);
  wp[2] = make_uint4(d[8], d[9], d[10], d[11]);
  wp[3] = make_uint4(d[12], d[13], 0u, 0u);
}

template <bool STORE_E>
__global__ __launch_bounds__(256, 4) void k_build(
    const float* __restrict__ obs, const float* __restrict__ feat,
    const float* __restrict__ pp, float* __restrict__ Rg,
    uint4* __restrict__ wsE) {
  const int gc = blockIdx.x * 256 + threadIdx.x;  // chunk id, kB*kNC total
  const int b = gc >> 10, cc = gc & (kNC - 1);
  const size_t t0 = (size_t)b * kT + (size_t)cc * kC;
  float R[25], sc;
  {
    float E[25], c;
    if (cc == 0) buildE0(obs, pp, b, E, c);
    else buildE(obs, feat, pp, t0, E, c);
    if (STORE_E) packE(wsE, t0, E, c);
#pragma unroll
    for (int e = 0; e < 25; ++e) R[e] = E[e];
    sc = c;
  }
#pragma unroll 1
  for (int k = 1; k < kC; ++k) {
    float E[25], c;
    buildE(obs, feat, pp, t0 + k, E, c);
    if (STORE_E) packE(wsE, t0 + k, E, c);
    sc += c;
    matmat5(R, E);
    rescale25(R, sc);
  }
  float4* o4 = reinterpret_cast<float4*>(Rg + (size_t)gc * 28);
  o4[0] = make_float4(R[0], R[1], R[2], R[3]);
  o4[1] = make_float4(R[4], R[5], R[6], R[7]);
  o4[2] = make_float4(R[8], R[9], R[10], R[11]);
  o4[3] = make_float4(R[12], R[13], R[14], R[15]);
  o4[4] = make_float4(R[16], R[17], R[18], R[19]);
  o4[5] = make_float4(R[20], R[21], R[22], R[23]);
  o4[6] = make_float4(R[24], sc, 0.f, 0.f);
}

__device__ __forceinline__ void loadRec(const float* __restrict__ base, size_t rec,
                                        float M[25], float& msc) {
  const float4* src = reinterpret_cast<const float4*>(base + rec * 28);
  float4 q[7];
#pragma unroll
  for (int i = 0; i < 7; ++i) q[i] = src[i];
  const float* v = reinterpret_cast<const float*>(q);
#pragma unroll
  for (int e = 0; e < 25; ++e) M[e] = v[e];
  msc = v[25];
}

// 3-level scan over 1024 records per b: fold4 (256 thr) -> fold8 (32 thr) ->
// serial 32 (1 thr) -> prefixes back down -> start[b][c], LL[b].
__global__ __launch_bounds__(256) void k_scan(const float* __restrict__ Rg,
                                              float* __restrict__ start,
                                              float* __restrict__ out) {
  __shared__ float sA[256 * 29];  // level-1 products (stride 29 to spread banks)
  __shared__ float sB[32 * 28];   // level-2 products
  __shared__ float sPB[32 * 8];   // level-2 prefixes (alpha,ls)
  __shared__ float sPA[256 * 8];  // level-1 prefixes
  const int b = blockIdx.x, j = threadIdx.x;
  const float* Rb = Rg + (size_t)b * kNC * 28;
  // L1: fold records 4j..4j+3
  float A[25], asc;
  loadRec(Rb, (size_t)(4 * j), A, asc);
#pragma unroll 1
  for (int k = 1; k < 4; ++k) {
    float M[25], msc;
    loadRec(Rb, (size_t)(4 * j + k), M, msc);
    asc += msc;
    matmat5(A, M);
    if (k >= 2) rescale25(A, asc);
  }
#pragma unroll
  for (int e = 0; e < 25; ++e) sA[j * 29 + e] = A[e];
  sA[j * 29 + 25] = asc;
  __syncthreads();
  // L2: fold 8 level-1 products
  if (j < 32) {
    float Bm[25], bsc;
#pragma unroll
    for (int e = 0; e < 25; ++e) Bm[e] = sA[(8 * j) * 29 + e];
    bsc = sA[(8 * j) * 29 + 25];
#pragma unroll 1
    for (int k = 1; k < 8; ++k) {
      float M[25];
#pragma unroll
      for (int e = 0; e < 25; ++e) M[e] = sA[(8 * j + k) * 29 + e];
      bsc += sA[(8 * j + k) * 29 + 25];
      matmat5(Bm, M);
      if (k & 1) rescale25(Bm, bsc);
    }
#pragma unroll
    for (int e = 0; e < 25; ++e) sB[j * 28 + e] = Bm[e];
    sB[j * 28 + 25] = bsc;
  }
  __syncthreads();
  // L3: serial scan over 32 group products; also emits LL
  if (j == 0) {
    float a[5] = {1.f, 1.f, 1.f, 1.f, 1.f};
    float ls = 0.f;
#pragma unroll 1
    for (int g = 0; g < 32; ++g) {
#pragma unroll
      for (int s = 0; s < 5; ++s) sPB[g * 8 + s] = a[s];
      sPB[g * 8 + 5] = ls;
      float M[25];
#pragma unroll
      for (int e = 0; e < 25; ++e) M[e] = sB[g * 28 + e];
      vecmat5(a, M);
      ls += sB[g * 28 + 25];
      rescale5(a, ls);
    }
    out[b] = (__log2f(a[0] + a[1] + a[2] + a[3] + a[4]) + ls) * kLn2;
  }
  __syncthreads();
  // L4: prefixes within each group of 8 level-1 products
  if (j < 32) {
    float a[5], ls;
#pragma unroll
    for (int s = 0; s < 5; ++s) a[s] = sPB[j * 8 + s];
    ls = sPB[j * 8 + 5];
#pragma unroll 1
    for (int q = 0; q < 8; ++q) {
      const int idx = 8 * j + q;
#pragma unroll
      for (int s = 0; s < 5; ++s) sPA[idx * 8 + s] = a[s];
      sPA[idx * 8 + 5] = ls;
      float M[25];
#pragma unroll
      for (int e = 0; e < 25; ++e) M[e] = sA[idx * 29 + e];
      vecmat5(a, M);
      ls += sA[idx * 29 + 25];
      rescale5(a, ls);
    }
  }
  __syncthreads();
  // L5: per-record prefixes -> start[b][c]
  {
    float a[5], ls;
#pragma unroll
    for (int s = 0; s < 5; ++s) a[s] = sPA[j * 8 + s];
    ls = sPA[j * 8 + 5];
#pragma unroll 1
    for (int k = 0; k < 4; ++k) {
      const int r = 4 * j + k;
      float* st = start + ((size_t)b * kNC + r) * 8;
      reinterpret_cast<float4*>(st)[0] = make_float4(a[0], a[1], a[2], a[3]);
      reinterpret_cast<float4*>(st)[1] = make_float4(a[4], ls, 0.f, 0.f);
      float M[25], msc;
      loadRec(Rb, (size_t)r, M, msc);
      vecmat5(a, M);
      ls += msc;
      rescale5(a, ls);
    }
  }
}

// variant A: stream bf16 E records; one lane per chunk
__global__ __launch_bounds__(256) void k_alpha_a(const uint4* __restrict__ wsE,
                                                 const float* __restrict__ start,
                                                 float* __restrict__ outp) {
  const int gc = blockIdx.x * 256 + threadIdx.x;
  const int b = gc >> 10, cc = gc & (kNC - 1);
  const float* st = start + (size_t)gc * 8;
  const float4 s0 = reinterpret_cast<const float4*>(st)[0];
  const float4 s1 = reinterpret_cast<const float4*>(st)[1];
  float a[5] = {s0.x, s0.y, s0.z, s0.w, s1.x};
  float ls = s1.y;
  float ov[20];
  const uint4* ep = wsE + ((size_t)b * kT + (size_t)cc * kC) * 4;
#pragma unroll
  for (int k = 0; k < 4; ++k) {
    uint4 q0 = ep[k * 4], q1 = ep[k * 4 + 1], q2 = ep[k * 4 + 2], q3 = ep[k * 4 + 3];
    unsigned d[14] = {q0.x, q0.y, q0.z, q0.w, q1.x, q1.y, q1.z, q1.w,
                      q2.x, q2.y, q2.z, q2.w, q3.x, q3.y};
    float E[25];
#pragma unroll
    for (int q = 0; q < 12; ++q) {
      E[2 * q]     = __uint_as_float(d[q] << 16);
      E[2 * q + 1] = __uint_as_float(d[q] & 0xffff0000u);
    }
    E[24] = __uint_as_float(d[12] << 16);
    const float cst = __uint_as_float((d[12] >> 16) | (d[13] << 16));
    float o[5];
#pragma unroll
    for (int j = 0; j < 5; ++j) {
      float acc = a[0] * E[j];
      acc = fmaf(a[1], E[5 + j], acc);
      acc = fmaf(a[2], E[10 + j], acc);
      acc = fmaf(a[3], E[15 + j], acc);
      acc = fmaf(a[4], E[20 + j], acc);
      o[j] = acc;
    }
    ls += cst;
    float L[5];
#pragma unroll
    for (int j = 0; j < 5; ++j) L[j] = __log2f(o[j]);
#pragma unroll
    for (int j = 0; j < 5; ++j) ov[k * 5 + j] = (L[j] + ls) * kLn2;
    const float lm = max5(L[0], L[1], L[2], L[3], L[4]);
    const float m = fmaxf(max5(o[0], o[1], o[2], o[3], o[4]), 1e-30f);
    const float r = __builtin_amdgcn_rcpf(m);
#pragma unroll
    for (int j = 0; j < 5; ++j) a[j] = o[j] * r;
    ls += lm;
  }
  float4* w = reinterpret_cast<float4*>(outp + kB + ((size_t)b * kT + (size_t)cc * kC) * kS);
#pragma unroll
  for (int q = 0; q < 5; ++q)
    w[q] = make_float4(ov[q * 4], ov[q * 4 + 1], ov[q * 4 + 2], ov[q * 4 + 3]);
}

// variant B: rebuild E (SGPR params); fallback when ws too small
__global__ __launch_bounds__(256, 4) void k_alpha_b(
    const float* __restrict__ obs, const float* __restrict__ feat,
    const float* __restrict__ pp, const float* __restrict__ start,
    float* __restrict__ outp) {
  const int gc = blockIdx.x * 256 + threadIdx.x;
  const int b = gc >> 10, cc = gc & (kNC - 1);
  const size_t t0 = (size_t)b * kT + (size_t)cc * kC;
  const float* st = start + (size_t)gc * 8;
  const float4 s0 = reinterpret_cast<const float4*>(st)[0];
  const float4 s1 = reinterpret_cast<const float4*>(st)[1];
  float a[5] = {s0.x, s0.y, s0.z, s0.w, s1.x};
  float ls = s1.y;
#pragma unroll 1
  for (int k = 0; k < 4; ++k) {
    float E[25], c;
    if (cc == 0 && k == 0) buildE0(obs, pp, b, E, c);
    else buildE(obs, feat, pp, t0 + k, E, c);
    float o[5];
#pragma unroll
    for (int j = 0; j < 5; ++j) {
      float acc = a[0] * E[j];
      acc = fmaf(a[1], E[5 + j], acc);
      acc = fmaf(a[2], E[10 + j], acc);
      acc = fmaf(a[3], E[15 + j], acc);
      acc = fmaf(a[4], E[20 + j], acc);
      o[j] = acc;
    }
    ls += c;
    float L[5];
#pragma unroll
    for (int j = 0; j < 5; ++j) L[j] = __log2f(o[j]);
    float* w = outp + kB + (t0 + k) * kS;
#pragma unroll
    for (int j = 0; j < 5; ++j) w[j] = (L[j] + ls) * kLn2;
    const float lm = max5(L[0], L[1], L[2], L[3], L[4]);
    const float m = fmaxf(max5(o[0], o[1], o[2], o[3], o[4]), 1e-30f);
    const float r = __builtin_amdgcn_rcpf(m);
#pragma unroll
    for (int j = 0; j < 5; ++j) a[j] = o[j] * r;
    ls += lm;
  }
}

}  // namespace

extern "C" void kernel_launch(void* const* d_in, const int* in_sizes, int n_in,
                              void* d_out, int out_size, void* d_ws, size_t ws_size,
                              hipStream_t stream) {
  (void)in_sizes; (void)n_in; (void)out_size;
  const float* obs   = (const float*)d_in[0];
  const float* feat  = (const float*)d_in[1];
  const float* means = (const float*)d_in[2];
  const float* lv    = (const float*)d_in[3];
  const float* linit = (const float*)d_in[4];
  const float* tbias = (const float*)d_in[5];
  const float* W1g   = (const float*)d_in[6];
  const float* b1g   = (const float*)d_in[7];
  const float* W2g   = (const float*)d_in[8];
  const float* b2g   = (const float*)d_in[9];
  float* out = (float*)d_out;

  // ws layout (floats): P 1024 | Rg kB*kNC*28 | start kB*kNC*8 | wsE (bytes)
  float* P     = (float*)d_ws;
  float* Rg    = P + P_TOT;
  float* start = Rg + (size_t)kB * kNC * 28;
  uint4* wsE   = reinterpret_cast<uint4*>(start + (size_t)kB * kNC * 8);
  const size_t needA = ((size_t)P_TOT + (size_t)kB * kNC * 28 + (size_t)kB * kNC * 8) * 4 +
                       (size_t)kB * kT * 64;
  const bool useA = ws_size >= needA;

  const int nBlk = (kB * kNC) / 256;  // 1024
  k_prep<<<1, 256, 0, stream>>>(means, lv, linit, tbias, W1g, b1g, W2g, b2g, P);
  if (useA) {
    k_build<true><<<nBlk, 256, 0, stream>>>(obs, feat, P, Rg, wsE);
  } else {
    k_build<false><<<nBlk, 256, 0, stream>>>(obs, feat, P, Rg, wsE);
  }
  k_scan<<<kB, 256, 0, stream>>>(Rg, start, out);
  if (useA) {
    k_alpha_a<<<nBlk, 256, 0, stream>>>(wsE, start, out);
  } else {
    k_alpha_b<<<nBlk, 256, 0, stream>>>(obs, feat, P, start, out);
  }
}

// Round 6
// 117.601 us; speedup vs baseline: 1.1819x; 1.1819x over previous
//
#include <hip/hip_runtime.h>
#include <math.h>

// MarketRegimeHMM forward via chunked associative scan — linear-domain semiring,
// base-2 scales.
//   k_prep  : 1 block; preprocess ~713 params into ws (scaled for exp2 forms).
//   k_build : one LANE per chunk (C=4).  Params staged once into 3KB LDS.
//             E matrices built TWO t AT A TIME (each param ds_read feeds both
//             t's FMAs -> half the load traffic, double the load ILP), folded
//             in registers (125 FMA/matmat) with rescale-by-max.  launch_bounds
//             (256,2) gives the RA a 256-VGPR budget so loads batch deeply
//             (R3-R5 were stuck at 56 VGPR = latency-bound on param loads).
//   k_scan  : one block per b: 3-level scan over 1024 records -> start[b][c],
//             LL[b].
//   k_alpha : one lane per chunk: stream bf16 E from ws, 25 FMA + 5 log2 per t.

namespace {

constexpr int kS = 5, kD = 16, kB = 256, kT = 4096;
constexpr int kC = 4, kNC = 1024;  // chunks per batch element

constexpr float kL2E = 1.4426950408889634f;  // 1/ln2
constexpr float kLn2 = 0.6931471805599453f;

// prep region offsets (floats)
constexpr int P_EA = 0;    // 80  -0.5*inv_v/ln2            [s*16+d]
constexpr int P_MU = 80;   // 80  means (raw)               [s*16+d]
constexpr int P_EC = 160;  // 5   -0.5*(16ln2pi + sum lv)/ln2
constexpr int P_LN = 168;  // 5   log2_softmax(log_initial)
constexpr int P_W1 = 176;  // 200 (2/ln2)*W1                [(i*10+h)*4+f]
constexpr int P_B1 = 376;  // 50  (2/ln2)*b1                [i*10+h]
constexpr int P_W2 = 432;  // 250 W2/ln2                    [(i*5+j)*10+h]
constexpr int P_B2 = 688;  // 25  (b2+tbias)/ln2            [i*5+j]
constexpr int P_TOT = 768;   // staged floats (3KB)
constexpr int P_RSV = 1024;  // reserved in ws

__device__ __forceinline__ float max5(float a0, float a1, float a2, float a3, float a4) {
  return fmaxf(fmaxf(fmaxf(a0, a1), fmaxf(a2, a3)), a4);
}

__device__ __forceinline__ void loadObs(const float* __restrict__ obs_bt, float* o) {
  const float4* o4 = reinterpret_cast<const float4*>(obs_bt);
  float4 v0 = o4[0], v1 = o4[1], v2 = o4[2], v3 = o4[3];
  o[0] = v0.x; o[1] = v0.y; o[2] = v0.z; o[3] = v0.w;
  o[4] = v1.x; o[5] = v1.y; o[6] = v1.z; o[7] = v1.w;
  o[8] = v2.x; o[9] = v2.y; o[10] = v2.z; o[11] = v2.w;
  o[12] = v3.x; o[13] = v3.y; o[14] = v3.z; o[15] = v3.w;
}

__device__ __forceinline__ unsigned bf16bits(float x) {
  unsigned u = __float_as_uint(x);
  return (u + 0x7fffu + ((u >> 16) & 1u)) >> 16;  // RTNE
}

__global__ void k_prep(const float* __restrict__ means, const float* __restrict__ lv,
                       const float* __restrict__ linit, const float* __restrict__ tbias,
                       const float* __restrict__ W1g, const float* __restrict__ b1g,
                       const float* __restrict__ W2g, const float* __restrict__ b2g,
                       float* __restrict__ P) {
  const int tid = threadIdx.x;  // 256
  if (tid < 80) {
    float iv = __expf(-lv[tid]);
    P[P_EA + tid] = -0.5f * kL2E * iv;
    P[P_MU + tid] = means[tid];
  }
  if (tid >= 80 && tid < 85) {
    const int s = tid - 80;
    float acc = 0.f;
#pragma unroll
    for (int d = 0; d < 16; ++d) acc += lv[s * 16 + d];
    P[P_EC + s] = -0.5f * kL2E * (29.406033062549525f + acc);  // 16*ln(2pi)+sum
    float l0 = linit[0], l1 = linit[1], l2 = linit[2], l3 = linit[3], l4 = linit[4];
    float m = max5(l0, l1, l2, l3, l4);
    float se = __expf(l0 - m) + __expf(l1 - m) + __expf(l2 - m) +
               __expf(l3 - m) + __expf(l4 - m);
    P[P_LN + s] = kL2E * (linit[s] - (m + __logf(se)));
  }
  if (tid < 200) P[P_W1 + tid] = (2.0f * kL2E) * W1g[tid];
  if (tid < 50)  P[P_B1 + tid] = (2.0f * kL2E) * b1g[tid];
  if (tid < 250) P[P_W2 + tid] = kL2E * W2g[tid];
  if (tid < 25)  P[P_B2 + tid] = kL2E * (b2g[tid] + tbias[tid]);
  if (tid >= 225 && tid < 225 + (P_TOT - 713)) {
    P[713 + tid - 225] = 0.f;  // pad so the LDS float4 stage reads defined data
  }
}

// Two E matrices from one pass over the parameters (each param read serves
// both timesteps).  p points to LDS; all offsets literal -> broadcast ds_read.
__device__ __forceinline__ void buildE2(const float* __restrict__ obs,
                                        const float* __restrict__ feat,
                                        const float* __restrict__ p,
                                        size_t bt, float Ea[25], float& ca,
                                        float Eb[25], float& cb) {
  float o[32];
  loadObs(obs + bt * kD, o);
  loadObs(obs + (bt + 1) * kD, o + 16);
  float lea[5], leb[5];
#pragma unroll
  for (int s = 0; s < 5; ++s) {
    float acca = p[P_EC + s];
    float accb = acca;
#pragma unroll
    for (int d = 0; d < 16; ++d) {
      const float mu = p[P_MU + s * 16 + d];
      const float aa = p[P_EA + s * 16 + d];
      const float da = o[d] - mu;
      const float db = o[16 + d] - mu;
      acca = fmaf(da, da * aa, acca);
      accb = fmaf(db, db * aa, accb);
    }
    lea[s] = acca; leb[s] = accb;
  }
  ca = max5(lea[0], lea[1], lea[2], lea[3], lea[4]);
  cb = max5(leb[0], leb[1], leb[2], leb[3], leb[4]);
  float emla[5], emlb[5];
#pragma unroll
  for (int j = 0; j < 5; ++j) {
    emla[j] = exp2f(lea[j] - ca);
    emlb[j] = exp2f(leb[j] - cb);
  }
  const float4 fa = *reinterpret_cast<const float4*>(feat + bt * 4);
  const float4 fb = *reinterpret_cast<const float4*>(feat + (bt + 1) * 4);
#pragma unroll
  for (int i = 0; i < 5; ++i) {
    float hva[10], hvb[10];
#pragma unroll
    for (int h = 0; h < 10; ++h) {
      const float w0 = p[P_W1 + (i * 10 + h) * 4 + 0];
      const float w1 = p[P_W1 + (i * 10 + h) * 4 + 1];
      const float w2 = p[P_W1 + (i * 10 + h) * 4 + 2];
      const float w3 = p[P_W1 + (i * 10 + h) * 4 + 3];
      const float bb = p[P_B1 + i * 10 + h];
      float acca = fmaf(fa.x, w0, bb), accb = fmaf(fb.x, w0, bb);
      acca = fmaf(fa.y, w1, acca);  accb = fmaf(fb.y, w1, accb);
      acca = fmaf(fa.z, w2, acca);  accb = fmaf(fb.z, w2, accb);
      acca = fmaf(fa.w, w3, acca);  accb = fmaf(fb.w, w3, accb);
      const float ea = exp2f(acca), eb = exp2f(accb);  // = exp(2x)
      hva[h] = 1.f - 2.f * __builtin_amdgcn_rcpf(ea + 1.f);  // tanh
      hvb[h] = 1.f - 2.f * __builtin_amdgcn_rcpf(eb + 1.f);
    }
    float ega[5], egb[5], sea = 0.f, seb = 0.f;
#pragma unroll
    for (int j = 0; j < 5; ++j) {
      const float b2 = p[P_B2 + i * 5 + j];
      float acca = b2, accb = b2;
#pragma unroll
      for (int h = 0; h < 10; ++h) {
        const float w = p[P_W2 + (i * 5 + j) * 10 + h];
        acca = fmaf(hva[h], w, acca);
        accb = fmaf(hvb[h], w, accb);
      }
      ega[j] = exp2f(acca); sea += ega[j];
      egb[j] = exp2f(accb); seb += egb[j];
    }
    const float rsa = __builtin_amdgcn_rcpf(sea);
    const float rsb = __builtin_amdgcn_rcpf(seb);
#pragma unroll
    for (int j = 0; j < 5; ++j) {
      Ea[i * 5 + j] = ega[j] * rsa * emla[j];
      Eb[i * 5 + j] = egb[j] * rsb * emlb[j];
    }
  }
}

// single-t variant (used only around the t=0 pseudo-record)
__device__ __forceinline__ void buildE(const float* __restrict__ obs,
                                       const float* __restrict__ feat,
                                       const float* __restrict__ p,
                                       size_t bt, float E[25], float& c) {
  float o[16];
  loadObs(obs + bt * kD, o);
  float le[5];
#pragma unroll
  for (int s = 0; s < 5; ++s) {
    float acc = p[P_EC + s];
#pragma unroll
    for (int d = 0; d < 16; ++d) {
      const float dd = o[d] - p[P_MU + s * 16 + d];
      acc = fmaf(dd, dd * p[P_EA + s * 16 + d], acc);
    }
    le[s] = acc;
  }
  c = max5(le[0], le[1], le[2], le[3], le[4]);
  float eml[5];
#pragma unroll
  for (int j = 0; j < 5; ++j) eml[j] = exp2f(le[j] - c);
  const float4 f = *reinterpret_cast<const float4*>(feat + bt * 4);
#pragma unroll
  for (int i = 0; i < 5; ++i) {
    float hv[10];
#pragma unroll
    for (int h = 0; h < 10; ++h) {
      float acc = p[P_B1 + i * 10 + h];
      acc = fmaf(f.x, p[P_W1 + (i * 10 + h) * 4 + 0], acc);
      acc = fmaf(f.y, p[P_W1 + (i * 10 + h) * 4 + 1], acc);
      acc = fmaf(f.z, p[P_W1 + (i * 10 + h) * 4 + 2], acc);
      acc = fmaf(f.w, p[P_W1 + (i * 10 + h) * 4 + 3], acc);
      const float e = exp2f(acc);
      hv[h] = 1.f - 2.f * __builtin_amdgcn_rcpf(e + 1.f);
    }
    float eg[5], se = 0.f;
#pragma unroll
    for (int j = 0; j < 5; ++j) {
      float acc = p[P_B2 + i * 5 + j];
#pragma unroll
      for (int h = 0; h < 10; ++h)
        acc = fmaf(hv[h], p[P_W2 + (i * 5 + j) * 10 + h], acc);
      eg[j] = exp2f(acc);
      se += eg[j];
    }
    const float rs = __builtin_amdgcn_rcpf(se);
#pragma unroll
    for (int j = 0; j < 5; ++j) E[i * 5 + j] = eg[j] * rs * eml[j];
  }
}

// pseudo-record for t=0: ones (x) E0 = linear alpha_0 (log2-scaled by c)
__device__ __forceinline__ void buildE0(const float* __restrict__ obs,
                                        const float* __restrict__ p, int b,
                                        float E[25], float& c) {
  float o[16];
  loadObs(obs + (size_t)b * kT * kD, o);
  float v[5];
#pragma unroll
  for (int s = 0; s < 5; ++s) {
    float acc = p[P_EC + s];
#pragma unroll
    for (int d = 0; d < 16; ++d) {
      const float dd = o[d] - p[P_MU + s * 16 + d];
      acc = fmaf(dd, dd * p[P_EA + s * 16 + d], acc);
    }
    v[s] = acc + p[P_LN + s];
  }
  c = max5(v[0], v[1], v[2], v[3], v[4]);
  float e[5];
#pragma unroll
  for (int j = 0; j < 5; ++j) e[j] = 0.2f * exp2f(v[j] - c);
#pragma unroll
  for (int i = 0; i < 5; ++i)
#pragma unroll
    for (int j = 0; j < 5; ++j) E[i * 5 + j] = e[j];
}

__device__ __forceinline__ void matmat5(float R[25], const float E[25]) {
#pragma unroll
  for (int i = 0; i < 5; ++i) {
    const float r0 = R[i * 5 + 0], r1 = R[i * 5 + 1], r2 = R[i * 5 + 2];
    const float r3 = R[i * 5 + 3], r4 = R[i * 5 + 4];
#pragma unroll
    for (int j = 0; j < 5; ++j) {
      float acc = r0 * E[j];
      acc = fmaf(r1, E[5 + j], acc);
      acc = fmaf(r2, E[10 + j], acc);
      acc = fmaf(r3, E[15 + j], acc);
      acc = fmaf(r4, E[20 + j], acc);
      R[i * 5 + j] = acc;
    }
  }
}

__device__ __forceinline__ void rescale25(float R[25], float& sc) {
  float m = R[0];
#pragma unroll
  for (int e = 1; e < 25; ++e) m = fmaxf(m, R[e]);
  m = fmaxf(m, 1e-30f);
  const float r = __builtin_amdgcn_rcpf(m);
#pragma unroll
  for (int e = 0; e < 25; ++e) R[e] *= r;
  sc += __log2f(m);
}

__device__ __forceinline__ void vecmat5(float a[5], const float M[25]) {
  float o[5];
#pragma unroll
  for (int j = 0; j < 5; ++j) {
    float acc = a[0] * M[j];
    acc = fmaf(a[1], M[5 + j], acc);
    acc = fmaf(a[2], M[10 + j], acc);
    acc = fmaf(a[3], M[15 + j], acc);
    acc = fmaf(a[4], M[20 + j], acc);
    o[j] = acc;
  }
#pragma unroll
  for (int j = 0; j < 5; ++j) a[j] = o[j];
}

__device__ __forceinline__ void rescale5(float a[5], float& ls) {
  const float m = fmaxf(max5(a[0], a[1], a[2], a[3], a[4]), 1e-30f);
  const float r = __builtin_amdgcn_rcpf(m);
#pragma unroll
  for (int j = 0; j < 5; ++j) a[j] *= r;
  ls += __log2f(m);
}

__device__ __forceinline__ void packE(uint4* __restrict__ wsE, size_t t,
                                      const float E[25], float c) {
  unsigned d[14];
#pragma unroll
  for (int q = 0; q < 12; ++q)
    d[q] = bf16bits(E[2 * q]) | (bf16bits(E[2 * q + 1]) << 16);
  const unsigned cb = __float_as_uint(c);
  d[12] = bf16bits(E[24]) | (cb << 16);
  d[13] = cb >> 16;
  uint4* wp = wsE + t * 4;
  wp[0] = make_uint4(d[0], d[1], d[2], d[3]);
  wp[1] = make_uint4(d[4], d[5], d[6], d[7]);
  wp[2] = make_uint4(d[8], d[9], d[10], d[11]);
  wp[3] = make_uint4(d[12], d[13], 0u, 0u);
}

template <bool STORE_E>
__global__ __launch_bounds__(256, 2) void k_build(
    const float* __restrict__ obs, const float* __restrict__ feat,
    const float* __restrict__ P, float* __restrict__ Rg,
    uint4* __restrict__ wsE) {
  __shared__ __align__(16) float p[P_TOT];
  if (threadIdx.x < P_TOT / 4)
    reinterpret_cast<float4*>(p)[threadIdx.x] =
        reinterpret_cast<const float4*>(P)[threadIdx.x];
  __syncthreads();
  const int gc = blockIdx.x * 256 + threadIdx.x;  // chunk id, kB*kNC total
  const int b = gc >> 10, cc = gc & (kNC - 1);
  const size_t t0 = (size_t)b * kT + (size_t)cc * kC;
  float R[25], sc;
  {
    float Ea[25], Eb[25], ca, cb;
    if (cc == 0) {
      buildE0(obs, p, b, Ea, ca);
      buildE(obs, feat, p, t0 + 1, Eb, cb);
    } else {
      buildE2(obs, feat, p, t0, Ea, ca, Eb, cb);
    }
    if (STORE_E) { packE(wsE, t0, Ea, ca); packE(wsE, t0 + 1, Eb, cb); }
#pragma unroll
    for (int e = 0; e < 25; ++e) R[e] = Ea[e];
    sc = ca + cb;
    matmat5(R, Eb);
    rescale25(R, sc);
  }
  {
    float Ea[25], Eb[25], ca, cb;
    buildE2(obs, feat, p, t0 + 2, Ea, ca, Eb, cb);
    if (STORE_E) { packE(wsE, t0 + 2, Ea, ca); packE(wsE, t0 + 3, Eb, cb); }
    sc += ca;
    matmat5(R, Ea);
    rescale25(R, sc);
    sc += cb;
    matmat5(R, Eb);
    rescale25(R, sc);
  }
  float4* o4 = reinterpret_cast<float4*>(Rg + (size_t)gc * 28);
  o4[0] = make_float4(R[0], R[1], R[2], R[3]);
  o4[1] = make_float4(R[4], R[5], R[6], R[7]);
  o4[2] = make_float4(R[8], R[9], R[10], R[11]);
  o4[3] = make_float4(R[12], R[13], R[14], R[15]);
  o4[4] = make_float4(R[16], R[17], R[18], R[19]);
  o4[5] = make_float4(R[20], R[21], R[22], R[23]);
  o4[6] = make_float4(R[24], sc, 0.f, 0.f);
}

__device__ __forceinline__ void loadRec(const float* __restrict__ base, size_t rec,
                                        float M[25], float& msc) {
  const float4* src = reinterpret_cast<const float4*>(base + rec * 28);
  float4 q[7];
#pragma unroll
  for (int i = 0; i < 7; ++i) q[i] = src[i];
  const float* v = reinterpret_cast<const float*>(q);
#pragma unroll
  for (int e = 0; e < 25; ++e) M[e] = v[e];
  msc = v[25];
}

// 3-level scan over 1024 records per b: fold4 (256 thr) -> fold8 (32 thr) ->
// serial 32 (1 thr) -> prefixes back down -> start[b][c], LL[b].
__global__ __launch_bounds__(256) void k_scan(const float* __restrict__ Rg,
                                              float* __restrict__ start,
                                              float* __restrict__ out) {
  __shared__ float sA[256 * 29];  // level-1 products
  __shared__ float sB[32 * 28];   // level-2 products
  __shared__ float sPB[32 * 8];   // level-2 prefixes (alpha,ls)
  __shared__ float sPA[256 * 8];  // level-1 prefixes
  const int b = blockIdx.x, j = threadIdx.x;
  const float* Rb = Rg + (size_t)b * kNC * 28;
  float A[25], asc;
  loadRec(Rb, (size_t)(4 * j), A, asc);
#pragma unroll 1
  for (int k = 1; k < 4; ++k) {
    float M[25], msc;
    loadRec(Rb, (size_t)(4 * j + k), M, msc);
    asc += msc;
    matmat5(A, M);
    if (k >= 2) rescale25(A, asc);
  }
#pragma unroll
  for (int e = 0; e < 25; ++e) sA[j * 29 + e] = A[e];
  sA[j * 29 + 25] = asc;
  __syncthreads();
  if (j < 32) {
    float Bm[25], bsc;
#pragma unroll
    for (int e = 0; e < 25; ++e) Bm[e] = sA[(8 * j) * 29 + e];
    bsc = sA[(8 * j) * 29 + 25];
#pragma unroll 1
    for (int k = 1; k < 8; ++k) {
      float M[25];
#pragma unroll
      for (int e = 0; e < 25; ++e) M[e] = sA[(8 * j + k) * 29 + e];
      bsc += sA[(8 * j + k) * 29 + 25];
      matmat5(Bm, M);
      if (k & 1) rescale25(Bm, bsc);
    }
#pragma unroll
    for (int e = 0; e < 25; ++e) sB[j * 28 + e] = Bm[e];
    sB[j * 28 + 25] = bsc;
  }
  __syncthreads();
  if (j == 0) {
    float a[5] = {1.f, 1.f, 1.f, 1.f, 1.f};
    float ls = 0.f;
#pragma unroll 1
    for (int g = 0; g < 32; ++g) {
#pragma unroll
      for (int s = 0; s < 5; ++s) sPB[g * 8 + s] = a[s];
      sPB[g * 8 + 5] = ls;
      float M[25];
#pragma unroll
      for (int e = 0; e < 25; ++e) M[e] = sB[g * 28 + e];
      vecmat5(a, M);
      ls += sB[g * 28 + 25];
      rescale5(a, ls);
    }
    out[b] = (__log2f(a[0] + a[1] + a[2] + a[3] + a[4]) + ls) * kLn2;
  }
  __syncthreads();
  if (j < 32) {
    float a[5], ls;
#pragma unroll
    for (int s = 0; s < 5; ++s) a[s] = sPB[j * 8 + s];
    ls = sPB[j * 8 + 5];
#pragma unroll 1
    for (int q = 0; q < 8; ++q) {
      const int idx = 8 * j + q;
#pragma unroll
      for (int s = 0; s < 5; ++s) sPA[idx * 8 + s] = a[s];
      sPA[idx * 8 + 5] = ls;
      float M[25];
#pragma unroll
      for (int e = 0; e < 25; ++e) M[e] = sA[idx * 29 + e];
      vecmat5(a, M);
      ls += sA[idx * 29 + 25];
      rescale5(a, ls);
    }
  }
  __syncthreads();
  {
    float a[5], ls;
#pragma unroll
    for (int s = 0; s < 5; ++s) a[s] = sPA[j * 8 + s];
    ls = sPA[j * 8 + 5];
#pragma unroll 1
    for (int k = 0; k < 4; ++k) {
      const int r = 4 * j + k;
      float* st = start + ((size_t)b * kNC + r) * 8;
      reinterpret_cast<float4*>(st)[0] = make_float4(a[0], a[1], a[2], a[3]);
      reinterpret_cast<float4*>(st)[1] = make_float4(a[4], ls, 0.f, 0.f);
      float M[25], msc;
      loadRec(Rb, (size_t)r, M, msc);
      vecmat5(a, M);
      ls += msc;
      rescale5(a, ls);
    }
  }
}

// variant A: stream bf16 E records; one lane per chunk
__global__ __launch_bounds__(256) void k_alpha_a(const uint4* __restrict__ wsE,
                                                 const float* __restrict__ start,
                                                 float* __restrict__ outp) {
  const int gc = blockIdx.x * 256 + threadIdx.x;
  const int b = gc >> 10, cc = gc & (kNC - 1);
  const float* st = start + (size_t)gc * 8;
  const float4 s0 = reinterpret_cast<const float4*>(st)[0];
  const float4 s1 = reinterpret_cast<const float4*>(st)[1];
  float a[5] = {s0.x, s0.y, s0.z, s0.w, s1.x};
  float ls = s1.y;
  float ov[20];
  const uint4* ep = wsE + ((size_t)b * kT + (size_t)cc * kC) * 4;
#pragma unroll
  for (int k = 0; k < 4; ++k) {
    uint4 q0 = ep[k * 4], q1 = ep[k * 4 + 1], q2 = ep[k * 4 + 2], q3 = ep[k * 4 + 3];
    unsigned d[14] = {q0.x, q0.y, q0.z, q0.w, q1.x, q1.y, q1.z, q1.w,
                      q2.x, q2.y, q2.z, q2.w, q3.x, q3.y};
    float E[25];
#pragma unroll
    for (int q = 0; q < 12; ++q) {
      E[2 * q]     = __uint_as_float(d[q] << 16);
      E[2 * q + 1] = __uint_as_float(d[q] & 0xffff0000u);
    }
    E[24] = __uint_as_float(d[12] << 16);
    const float cst = __uint_as_float((d[12] >> 16) | (d[13] << 16));
    float o[5];
#pragma unroll
    for (int j = 0; j < 5; ++j) {
      float acc = a[0] * E[j];
      acc = fmaf(a[1], E[5 + j], acc);
      acc = fmaf(a[2], E[10 + j], acc);
      acc = fmaf(a[3], E[15 + j], acc);
      acc = fmaf(a[4], E[20 + j], acc);
      o[j] = acc;
    }
    ls += cst;
    float L[5];
#pragma unroll
    for (int j = 0; j < 5; ++j) L[j] = __log2f(o[j]);
#pragma unroll
    for (int j = 0; j < 5; ++j) ov[k * 5 + j] = (L[j] + ls) * kLn2;
    const float lm = max5(L[0], L[1], L[2], L[3], L[4]);
    const float m = fmaxf(max5(o[0], o[1], o[2], o[3], o[4]), 1e-30f);
    const float r = __builtin_amdgcn_rcpf(m);
#pragma unroll
    for (int j = 0; j < 5; ++j) a[j] = o[j] * r;
    ls += lm;
  }
  float4* w = reinterpret_cast<float4*>(outp + kB + ((size_t)b * kT + (size_t)cc * kC) * kS);
#pragma unroll
  for (int q = 0; q < 5; ++q)
    w[q] = make_float4(ov[q * 4], ov[q * 4 + 1], ov[q * 4 + 2], ov[q * 4 + 3]);
}

// variant B: rebuild E (LDS params); fallback when ws too small
__global__ __launch_bounds__(256, 2) void k_alpha_b(
    const float* __restrict__ obs, const float* __restrict__ feat,
    const float* __restrict__ P, const float* __restrict__ start,
    float* __restrict__ outp) {
  __shared__ __align__(16) float p[P_TOT];
  if (threadIdx.x < P_TOT / 4)
    reinterpret_cast<float4*>(p)[threadIdx.x] =
        reinterpret_cast<const float4*>(P)[threadIdx.x];
  __syncthreads();
  const int gc = blockIdx.x * 256 + threadIdx.x;
  const int b = gc >> 10, cc = gc & (kNC - 1);
  const size_t t0 = (size_t)b * kT + (size_t)cc * kC;
  const float* st = start + (size_t)gc * 8;
  const float4 s0 = reinterpret_cast<const float4*>(st)[0];
  const float4 s1 = reinterpret_cast<const float4*>(st)[1];
  float a[5] = {s0.x, s0.y, s0.z, s0.w, s1.x};
  float ls = s1.y;
#pragma unroll 1
  for (int k = 0; k < 4; ++k) {
    float E[25], c;
    if (cc == 0 && k == 0) buildE0(obs, p, b, E, c);
    else buildE(obs, feat, p, t0 + k, E, c);
    float o[5];
#pragma unroll
    for (int j = 0; j < 5; ++j) {
      float acc = a[0] * E[j];
      acc = fmaf(a[1], E[5 + j], acc);
      acc = fmaf(a[2], E[10 + j], acc);
      acc = fmaf(a[3], E[15 + j], acc);
      acc = fmaf(a[4], E[20 + j], acc);
      o[j] = acc;
    }
    ls += c;
    float L[5];
#pragma unroll
    for (int j = 0; j < 5; ++j) L[j] = __log2f(o[j]);
    float* w = outp + kB + (t0 + k) * kS;
#pragma unroll
    for (int j = 0; j < 5; ++j) w[j] = (L[j] + ls) * kLn2;
    const float lm = max5(L[0], L[1], L[2], L[3], L[4]);
    const float m = fmaxf(max5(o[0], o[1], o[2], o[3], o[4]), 1e-30f);
    const float r = __builtin_amdgcn_rcpf(m);
#pragma unroll
    for (int j = 0; j < 5; ++j) a[j] = o[j] * r;
    ls += lm;
  }
}

}  // namespace

extern "C" void kernel_launch(void* const* d_in, const int* in_sizes, int n_in,
                              void* d_out, int out_size, void* d_ws, size_t ws_size,
                              hipStream_t stream) {
  (void)in_sizes; (void)n_in; (void)out_size;
  const float* obs   = (const float*)d_in[0];
  const float* feat  = (const float*)d_in[1];
  const float* means = (const float*)d_in[2];
  const float* lv    = (const float*)d_in[3];
  const float* linit = (const float*)d_in[4];
  const float* tbias = (const float*)d_in[5];
  const float* W1g   = (const float*)d_in[6];
  const float* b1g   = (const float*)d_in[7];
  const float* W2g   = (const float*)d_in[8];
  const float* b2g   = (const float*)d_in[9];
  float* out = (float*)d_out;

  // ws layout (floats): P 1024 | Rg kB*kNC*28 | start kB*kNC*8 | wsE (bytes)
  float* P     = (float*)d_ws;
  float* Rg    = P + P_RSV;
  float* start = Rg + (size_t)kB * kNC * 28;
  uint4* wsE   = reinterpret_cast<uint4*>(start + (size_t)kB * kNC * 8);
  const size_t needA = ((size_t)P_RSV + (size_t)kB * kNC * 28 + (size_t)kB * kNC * 8) * 4 +
                       (size_t)kB * kT * 64;
  const bool useA = ws_size >= needA;

  const int nBlk = (kB * kNC) / 256;  // 1024
  k_prep<<<1, 256, 0, stream>>>(means, lv, linit, tbias, W1g, b1g, W2g, b2g, P);
  if (useA) {
    k_build<true><<<nBlk, 256, 0, stream>>>(obs, feat, P, Rg, wsE);
  } else {
    k_build<false><<<nBlk, 256, 0, stream>>>(obs, feat, P, Rg, wsE);
  }
  k_scan<<<kB, 256, 0, stream>>>(Rg, start, out);
  if (useA) {
    k_alpha_a<<<nBlk, 256, 0, stream>>>(wsE, start, out);
  } else {
    k_alpha_b<<<nBlk, 256, 0, stream>>>(obs, feat, P, start, out);
  }
}